// Round 6
// baseline (130.174 us; speedup 1.0000x reference)
//
#include <hip/hip_runtime.h>

#define KDIM 1024
#define NDIM 16384
#define CHUNKS 256
#define CLEN 64   // NDIM / CHUNKS
#define KTILES 16 // KDIM / 64

typedef __bf16 bf16_t;
typedef bf16_t bf16x8 __attribute__((ext_vector_type(8)));
typedef bf16_t bf16x4 __attribute__((ext_vector_type(4)));
typedef float f32x4 __attribute__((ext_vector_type(4)));

__device__ __forceinline__ void gload_lds16(const bf16_t* g, bf16_t* l) {
  __builtin_amdgcn_global_load_lds(
      (const __attribute__((address_space(1))) void*)g,
      (__attribute__((address_space(3))) void*)l, 16, 0, 0);
}

// ---------------- fused: halpha fp32->bf16 (blocks >= 1024) + scan phase 1 ----------------
__global__ __launch_bounds__(256) void k_phase1(const float* __restrict__ obs,
                                                const float* __restrict__ hbeta,
                                                float* __restrict__ carry,
                                                float* __restrict__ psum,
                                                const float* __restrict__ A,
                                                bf16_t* __restrict__ Ab) {
  if (blockIdx.x >= 1024) {
    // halpha convert: 1024 blocks x 256 thr x 4 floats
    size_t i = ((size_t)(blockIdx.x - 1024) * 256 + threadIdx.x) * 4;
    float4 v = *reinterpret_cast<const float4*>(A + i);
    bf16x4 o;
    o[0] = (bf16_t)v.x; o[1] = (bf16_t)v.y; o[2] = (bf16_t)v.z; o[3] = (bf16_t)v.w;
    *reinterpret_cast<bf16x4*>(Ab + i) = o;
    return;
  }
  int tid = blockIdx.x * 256 + threadIdx.x;   // 0 .. K*CHUNKS-1
  int k = tid >> 8;                            // / CHUNKS
  int c = tid & (CHUNKS - 1);
  float beta = hbeta[0];
  float decay = expf(-beta);
  const float* p = obs + (size_t)k * NDIM + c * CLEN;
  float S = 0.f, sum = 0.f;
#pragma unroll
  for (int t = 0; t < CLEN; t += 4) {
    float4 v = *reinterpret_cast<const float4*>(p + t);
    S = decay * (S + beta * v.x);
    S = decay * (S + beta * v.y);
    S = decay * (S + beta * v.z);
    S = decay * (S + beta * v.w);
    sum += v.x + v.y + v.z + v.w;
  }
  carry[tid] = S;   // layout [k][c]
  psum[tid] = sum;
}

// ---------------- scan phase 2: exclusive prefix over chunk carries; hmu ----------------
__global__ __launch_bounds__(64) void k_phase2(const float* __restrict__ hbeta,
                                               float* __restrict__ carry,
                                               const float* __restrict__ psum,
                                               float* __restrict__ hmu) {
  int k = blockIdx.x * blockDim.x + threadIdx.x;
  if (k >= KDIM) return;
  float beta = hbeta[0];
  float dL = expf(-beta * (float)CLEN);   // decay^CLEN
  float Cg = 0.f, tot = 0.f;
  float* pc = carry + (size_t)k * CHUNKS;
  const float* pp = psum + (size_t)k * CHUNKS;
  for (int c = 0; c < CHUNKS; ++c) {
    float loc = pc[c];
    pc[c] = Cg;               // global S at chunk start
    Cg = dL * Cg + loc;
    tot += pp[c];
  }
  hmu[k] = tot * (1.0f / NDIM) * 0.1f + 0.01f;
}

// ---------------- scan phase 3: full scan with carry, write S_all [t][j] bf16 ----------------
__global__ __launch_bounds__(64) void k_phase3(const float* __restrict__ obs,
                                               const float* __restrict__ hbeta,
                                               const float* __restrict__ carry,
                                               bf16_t* __restrict__ S_all) {
  int c  = blockIdx.x & (CHUNKS - 1);
  int kb = blockIdx.x >> 8;
  int lane = threadIdx.x;
  float beta = hbeta[0];
  float decay = expf(-beta);
  __shared__ float  obs_s[64][65];
  __shared__ bf16_t out_s[64][72];
  int k0 = kb * 64, t0 = c * CLEN;
#pragma unroll 4
  for (int r = 0; r < 64; ++r)
    obs_s[r][lane] = obs[(size_t)(k0 + r) * NDIM + t0 + lane];
  __syncthreads();
  float S = carry[(size_t)(k0 + lane) * CHUNKS + c];
#pragma unroll 8
  for (int t = 0; t < CLEN; ++t) {
    out_s[t][lane] = (bf16_t)S;                 // S_all[t] is pre-update value
    S = decay * (S + beta * obs_s[lane][t]);
  }
  __syncthreads();
#pragma unroll 4
  for (int t = 0; t < CLEN; ++t)
    S_all[(size_t)(t0 + t) * KDIM + k0 + lane] = out_s[t][lane];
}

// ---------------- GEMM lam1 = halpha @ S_all^T, fused softplus + loglik ----------------
// 128x128 tile, BK=64, 256 threads (4 waves, 2Mx2N), LDS 64KB -> 2 blocks/CU for
// cross-block latency hiding. 2 barriers/tile, counted vmcnt(4) mid-loop,
// LDS XOR-swizzle via pre-swizzled GLOBAL source + swizzled ds_read, setprio on MFMA.
__global__ __launch_bounds__(256, 2) void k_gemm(const bf16_t* __restrict__ Ab,
                                                 const bf16_t* __restrict__ Bb,
                                                 const float* __restrict__ hmu,
                                                 const float* __restrict__ obs,
                                                 float* __restrict__ out) {
  __shared__ bf16_t As[2][128 * 64];
  __shared__ bf16_t Bs[2][128 * 64];
  int tid = threadIdx.x;
  // XCD-chunk swizzle: 1024 blocks, 8 XCDs, kb-fastest so the 8 blocks sharing a
  // B-panel sit on one XCD (B working set 16 panels * 256KB = 4MB = L2; A 2MB resident)
  int b = blockIdx.x;
  int lb = (b & 7) * 128 + (b >> 3);
  int kb = lb & 7;            // M-tile (8)
  int tb = lb >> 3;           // N-tile (128)
  int lane = tid & 63, wid = tid >> 6;
  int wm = wid >> 1, wn = wid & 1;          // 2x2 waves, each 64x64 output
  int r15 = lane & 15, h = lane >> 4;
  f32x4 acc[4][4] = {};

  // staging: slot = i*256 + tid; row = slot>>3; phys slot sp = slot&7;
  // global source uses logical slot sl = sp ^ (row&7)  (inverse-swizzle the source)
  const bf16_t* gA[4];
  const bf16_t* gB[4];
#pragma unroll
  for (int i = 0; i < 4; ++i) {
    int slot = i * 256 + tid;
    int row = slot >> 3, sp = slot & 7;
    int sl = sp ^ (row & 7);
    gA[i] = Ab + (size_t)(kb * 128 + row) * KDIM + sl * 8;
    gB[i] = Bb + (size_t)(tb * 128 + row) * KDIM + sl * 8;
  }

#define STAGE_A(buf, kkoff) do { \
  _Pragma("unroll") \
  for (int i = 0; i < 4; ++i) \
    gload_lds16(gA[i] + (kkoff), &As[buf][(i * 256 + wid * 64) * 8]); \
} while (0)
#define STAGE_B(buf, kkoff) do { \
  _Pragma("unroll") \
  for (int i = 0; i < 4; ++i) \
    gload_lds16(gB[i] + (kkoff), &Bs[buf][(i * 256 + wid * 64) * 8]); \
} while (0)

  // fragment address helpers (row-XOR swizzled)
#define A_FRAG(mi, sl) (*reinterpret_cast<const bf16x8*>( \
    &As[cur][(wm * 64 + (mi) * 16 + r15) * 64 + ((((sl)) ^ ((wm * 64 + (mi) * 16 + r15) & 7)) * 8)]))
#define B_FRAG(ni, sl) (*reinterpret_cast<const bf16x8*>( \
    &Bs[cur][(wn * 64 + (ni) * 16 + r15) * 64 + ((((sl)) ^ ((wn * 64 + (ni) * 16 + r15) & 7)) * 8)]))

  // prologue: stage tile 0 (8 load-instrs in flight)
  STAGE_A(0, 0);
  STAGE_B(0, 0);

  int cur = 0;
  for (int kt = 0; kt < KTILES; ++kt) {
    __builtin_amdgcn_sched_barrier(0);       // pin prev tile's reads above barrier (a)
    __builtin_amdgcn_s_barrier();            // (a) all waves done reading buf^1
    if (kt < KTILES - 1) {
      STAGE_A(cur ^ 1, (kt + 1) * 64);       // 4 loads into freed buf^1 A
      asm volatile("s_waitcnt vmcnt(4)" ::: "memory");  // tile kt's 8 loads retired
    } else {
      asm volatile("s_waitcnt vmcnt(0)" ::: "memory");
    }
    __builtin_amdgcn_s_barrier();            // (b) buf[cur] valid for all waves

    bf16x8 af[4], bf0[4];
    // ---- ph0: kh=0 ----
#pragma unroll
    for (int m = 0; m < 4; ++m) af[m] = A_FRAG(m, h);
#pragma unroll
    for (int n = 0; n < 4; ++n) bf0[n] = B_FRAG(n, h);
    __builtin_amdgcn_s_setprio(1);
#pragma unroll
    for (int m = 0; m < 4; ++m)
#pragma unroll
      for (int n = 0; n < 4; ++n)
        acc[m][n] = __builtin_amdgcn_mfma_f32_16x16x32_bf16(af[m], bf0[n], acc[m][n], 0, 0, 0);
    __builtin_amdgcn_s_setprio(0);
    // ---- stage next tile's B mid-tile (no reader until kt+1) ----
    if (kt < KTILES - 1) STAGE_B(cur ^ 1, (kt + 1) * 64);
    // ---- ph1: kh=1 ----
#pragma unroll
    for (int m = 0; m < 4; ++m) af[m] = A_FRAG(m, 4 + h);
#pragma unroll
    for (int n = 0; n < 4; ++n) bf0[n] = B_FRAG(n, 4 + h);
    __builtin_amdgcn_s_setprio(1);
#pragma unroll
    for (int m = 0; m < 4; ++m)
#pragma unroll
      for (int n = 0; n < 4; ++n)
        acc[m][n] = __builtin_amdgcn_mfma_f32_16x16x32_bf16(af[m], bf0[n], acc[m][n], 0, 0, 0);
    __builtin_amdgcn_s_setprio(0);
    cur ^= 1;
  }
#undef STAGE_A
#undef STAGE_B
#undef A_FRAG
#undef B_FRAG

  // epilogue: lams = softplus(hmu + lam1); loglik partial = obs*log(lams) - lams
  float lsum = 0.f;
  float* lams = out + 1;
#pragma unroll
  for (int mi = 0; mi < 4; ++mi) {
    int krow0 = kb * 128 + wm * 64 + mi * 16 + h * 4;
#pragma unroll
    for (int ni = 0; ni < 4; ++ni) {
      int t = tb * 128 + wn * 64 + ni * 16 + r15;
#pragma unroll
      for (int r = 0; r < 4; ++r) {
        int krow = krow0 + r;
        float x = hmu[krow] + acc[mi][ni][r];
        // stable cheap softplus: max(x,0) + log(1 + exp(-|x|))
        float lam = fmaxf(x, 0.f) + __logf(1.f + __expf(-fabsf(x)));
        lams[(size_t)krow * NDIM + t] = lam;
        float o = obs[(size_t)krow * NDIM + t];
        lsum += o * __logf(lam) - lam;
      }
    }
  }
  // reduce loglik
  lsum += __shfl_down(lsum, 32);
  lsum += __shfl_down(lsum, 16);
  lsum += __shfl_down(lsum, 8);
  lsum += __shfl_down(lsum, 4);
  lsum += __shfl_down(lsum, 2);
  lsum += __shfl_down(lsum, 1);
  __shared__ float wsum[4];
  if (lane == 0) wsum[wid] = lsum;
  __syncthreads();
  if (tid == 0) atomicAdd(out, wsum[0] + wsum[1] + wsum[2] + wsum[3]);
}

extern "C" void kernel_launch(void* const* d_in, const int* in_sizes, int n_in,
                              void* d_out, int out_size, void* d_ws, size_t ws_size,
                              hipStream_t stream) {
  const float* obs    = (const float*)d_in[0];
  const float* halpha = (const float*)d_in[1];
  const float* hbeta  = (const float*)d_in[2];
  float* out = (float*)d_out;

  char* ws = (char*)d_ws;
  bf16_t* S_all = (bf16_t*)ws;                                   // 32 MB, [NDIM][KDIM]
  float*  carry = (float*)(ws + (size_t)NDIM * KDIM * 2);        // 1 MB, [K][CHUNKS]
  float*  psum  = carry + (size_t)KDIM * CHUNKS;                 // 1 MB
  float*  hmu   = psum + (size_t)KDIM * CHUNKS;                  // 4 KB
  bf16_t* Ab    = (bf16_t*)(hmu + KDIM);                         // 2 MB

  hipMemsetAsync(d_out, 0, sizeof(float), stream);               // loglik accumulator
  k_phase1<<<2048, 256, 0, stream>>>(obs, hbeta, carry, psum, halpha, Ab);
  k_phase2<<<16, 64, 0, stream>>>(hbeta, carry, psum, hmu);
  k_phase3<<<(KDIM / 64) * CHUNKS, 64, 0, stream>>>(obs, hbeta, carry, S_all);
  k_gemm<<<8 * (NDIM / 128), 256, 0, stream>>>(Ab, S_all, hmu, obs, out);
}

// Round 7
// 107.169 us; speedup vs baseline: 1.2147x; 1.2147x over previous
//
#include <hip/hip_runtime.h>

#define KDIM 1024
#define NDIM 16384
#define CHUNKS 256
#define CLEN 64   // NDIM / CHUNKS
#define KTILES 16 // KDIM / 64

typedef __bf16 bf16_t;
typedef bf16_t bf16x8 __attribute__((ext_vector_type(8)));
typedef bf16_t bf16x4 __attribute__((ext_vector_type(4)));
typedef float f32x4 __attribute__((ext_vector_type(4)));

__device__ __forceinline__ void gload_lds16(const bf16_t* g, bf16_t* l) {
  __builtin_amdgcn_global_load_lds(
      (const __attribute__((address_space(1))) void*)g,
      (__attribute__((address_space(3))) void*)l, 16, 0, 0);
}

// ---------------- fused: scan phase1 (one k-row per block) + obs->u8 + halpha->bf16 ----------------
__global__ __launch_bounds__(256) void k_phase1(const float* __restrict__ obs,
                                                const float* __restrict__ hbeta,
                                                float* __restrict__ carry,
                                                float* __restrict__ psum,
                                                const float* __restrict__ A,
                                                bf16_t* __restrict__ Ab,
                                                unsigned char* __restrict__ obs8) {
  if (blockIdx.x >= 1024) {
    // halpha convert: 1024 blocks x 256 thr x 4 floats
    size_t i = ((size_t)(blockIdx.x - 1024) * 256 + threadIdx.x) * 4;
    float4 v = *reinterpret_cast<const float4*>(A + i);
    bf16x4 o;
    o[0] = (bf16_t)v.x; o[1] = (bf16_t)v.y; o[2] = (bf16_t)v.z; o[3] = (bf16_t)v.w;
    *reinterpret_cast<bf16x4*>(Ab + i) = o;
    return;
  }
  __shared__ unsigned char s8[256][68];   // padded: bank = (17c + t/4) % 32, conflict-free
  int i = threadIdx.x;                    // chunk index c
  int k = blockIdx.x;                     // one obs row per block
  float beta = hbeta[0];
  float decay = expf(-beta);
  const float* p = obs + (size_t)k * NDIM + i * CLEN;
  float S = 0.f, sum = 0.f;
#pragma unroll
  for (int t = 0; t < CLEN; t += 4) {
    float4 v = *reinterpret_cast<const float4*>(p + t);
    uchar4 u;
    u.x = (unsigned char)v.x; u.y = (unsigned char)v.y;
    u.z = (unsigned char)v.z; u.w = (unsigned char)v.w;
    *reinterpret_cast<uchar4*>(&s8[i][t]) = u;
    S = decay * (S + beta * v.x);
    S = decay * (S + beta * v.y);
    S = decay * (S + beta * v.z);
    S = decay * (S + beta * v.w);
    sum += v.x + v.y + v.z + v.w;
  }
  carry[(size_t)k * CHUNKS + i] = S;
  psum[(size_t)k * CHUNKS + i] = sum;
  __syncthreads();
  // coalesced obs8 writeout: 256 thr x 4B consecutive = 1KB per instr
  unsigned char* po = obs8 + (size_t)k * NDIM;
#pragma unroll
  for (int w = 0; w < 16; ++w) {
    int t = w * 1024 + i * 4;
    int c = t >> 6, off = t & 63;
    *reinterpret_cast<uchar4*>(po + t) = *reinterpret_cast<const uchar4*>(&s8[c][off]);
  }
}

// ---------------- scan phase 2: exclusive prefix over chunk carries; hmu ----------------
__global__ __launch_bounds__(64) void k_phase2(const float* __restrict__ hbeta,
                                               float* __restrict__ carry,
                                               const float* __restrict__ psum,
                                               float* __restrict__ hmu) {
  int k = blockIdx.x * blockDim.x + threadIdx.x;
  if (k >= KDIM) return;
  float beta = hbeta[0];
  float dL = expf(-beta * (float)CLEN);   // decay^CLEN
  float Cg = 0.f, tot = 0.f;
  float* pc = carry + (size_t)k * CHUNKS;
  const float* pp = psum + (size_t)k * CHUNKS;
  for (int c = 0; c < CHUNKS; ++c) {
    float loc = pc[c];
    pc[c] = Cg;               // global S at chunk start
    Cg = dL * Cg + loc;
    tot += pp[c];
  }
  hmu[k] = tot * (1.0f / NDIM) * 0.1f + 0.01f;
}

// ---------------- scan phase 3: full scan with carry (obs8 input), write S_all [t][j] bf16 ----------------
__global__ __launch_bounds__(64) void k_phase3(const unsigned char* __restrict__ obs8,
                                               const float* __restrict__ hbeta,
                                               const float* __restrict__ carry,
                                               bf16_t* __restrict__ S_all) {
  int c  = blockIdx.x & (CHUNKS - 1);
  int kb = blockIdx.x >> 8;
  int lane = threadIdx.x;
  float beta = hbeta[0];
  float decay = expf(-beta);
  __shared__ unsigned char s8[64][68];    // padded, conflict-free
  __shared__ bf16_t out_s[64][72];
  int k0 = kb * 64, t0 = c * CLEN;
  // load 64x64 byte tile: lane l -> row w*4+(l>>4), col (l&15)*4 (4 x 64B segments/instr)
  const unsigned char* base = obs8 + (size_t)k0 * NDIM + t0;
#pragma unroll 4
  for (int w = 0; w < 16; ++w) {
    int r = w * 4 + (lane >> 4), col = (lane & 15) * 4;
    *reinterpret_cast<uchar4*>(&s8[r][col]) =
        *reinterpret_cast<const uchar4*>(base + (size_t)r * NDIM + col);
  }
  __syncthreads();
  float S = carry[(size_t)(k0 + lane) * CHUNKS + c];
#pragma unroll 8
  for (int t = 0; t < CLEN; ++t) {
    out_s[t][lane] = (bf16_t)S;                 // S_all[t] is pre-update value
    S = decay * (S + beta * (float)s8[lane][t]);
  }
  __syncthreads();
#pragma unroll 4
  for (int t = 0; t < CLEN; ++t)
    S_all[(size_t)(t0 + t) * KDIM + k0 + lane] = out_s[t][lane];
}

// ---------------- GEMM lam1 = halpha @ S_all^T, fused softplus + loglik ----------------
// 256x256 tile, BK=64, 512 threads (8 waves, 2Mx4N). 2 barriers/tile, counted
// vmcnt(4) mid-loop (never 0 mid-loop); STAGE_A at tile head, STAGE_B mid-tile.
// LDS XOR-swizzle via pre-swizzled GLOBAL source + swizzled ds_read. setprio on MFMA.
__global__ __launch_bounds__(512, 2) void k_gemm(const bf16_t* __restrict__ Ab,
                                                 const bf16_t* __restrict__ Bb,
                                                 const float* __restrict__ hmu,
                                                 const unsigned char* __restrict__ obs8,
                                                 float* __restrict__ out) {
  __shared__ bf16_t As[2][256 * 64];
  __shared__ bf16_t Bs[2][256 * 64];
  int tid = threadIdx.x;
  // XCD-chunk swizzle: 256 blocks, 8 XCDs -> bijective
  int b = blockIdx.x;
  int lb = (b & 7) * 32 + (b >> 3);
  int kb = lb & 3;            // M-tile (4)
  int tb = lb >> 2;           // N-tile (64); 4 consecutive logical blocks share tb
  int lane = tid & 63, wid = tid >> 6;
  int wm = wid >> 2, wn = wid & 3;          // 2x4 waves, each 128x64 output
  int r15 = lane & 15, h = lane >> 4;
  f32x4 acc[8][4] = {};

  const bf16_t* gA[4];
  const bf16_t* gB[4];
#pragma unroll
  for (int i = 0; i < 4; ++i) {
    int slot = i * 512 + tid;
    int row = slot >> 3, sp = slot & 7;
    int sl = sp ^ (row & 7);
    gA[i] = Ab + (size_t)(kb * 256 + row) * KDIM + sl * 8;
    gB[i] = Bb + (size_t)(tb * 256 + row) * KDIM + sl * 8;
  }

#define STAGE_A(buf, kkoff) do { \
  _Pragma("unroll") \
  for (int i = 0; i < 4; ++i) \
    gload_lds16(gA[i] + (kkoff), &As[buf][(i * 512 + wid * 64) * 8]); \
} while (0)
#define STAGE_B(buf, kkoff) do { \
  _Pragma("unroll") \
  for (int i = 0; i < 4; ++i) \
    gload_lds16(gB[i] + (kkoff), &Bs[buf][(i * 512 + wid * 64) * 8]); \
} while (0)

#define A_FRAG(mi, sl) (*reinterpret_cast<const bf16x8*>( \
    &As[cur][(wm * 128 + (mi) * 16 + r15) * 64 + ((((sl)) ^ ((wm * 128 + (mi) * 16 + r15) & 7)) * 8)]))
#define B_FRAG(ni, sl) (*reinterpret_cast<const bf16x8*>( \
    &Bs[cur][(wn * 64 + (ni) * 16 + r15) * 64 + ((((sl)) ^ ((wn * 64 + (ni) * 16 + r15) & 7)) * 8)]))

  // prologue: stage tile 0 (8 loads in flight)
  STAGE_A(0, 0);
  STAGE_B(0, 0);

  int cur = 0;
  for (int kt = 0; kt < KTILES; ++kt) {
    __builtin_amdgcn_sched_barrier(0);       // pin prev tile's reads above barrier (a)
    __builtin_amdgcn_s_barrier();            // (a) all waves done reading buf^1
    if (kt < KTILES - 1) {
      STAGE_A(cur ^ 1, (kt + 1) * 64);       // 4 loads into freed buf^1 A
      asm volatile("s_waitcnt vmcnt(4)" ::: "memory");  // tile kt's 8 loads retired
    } else {
      asm volatile("s_waitcnt vmcnt(0)" ::: "memory");
    }
    __builtin_amdgcn_s_barrier();            // (b) buf[cur] valid for all waves

    bf16x8 a0[4], a1[4], bf0[4];
    // ---- ph0: kh=0, M-half 0 ----
#pragma unroll
    for (int m = 0; m < 4; ++m) a0[m] = A_FRAG(m, h);
#pragma unroll
    for (int n = 0; n < 4; ++n) bf0[n] = B_FRAG(n, h);
    __builtin_amdgcn_s_setprio(1);
#pragma unroll
    for (int m = 0; m < 4; ++m)
#pragma unroll
      for (int n = 0; n < 4; ++n)
        acc[m][n] = __builtin_amdgcn_mfma_f32_16x16x32_bf16(a0[m], bf0[n], acc[m][n], 0, 0, 0);
    __builtin_amdgcn_s_setprio(0);
    // ---- ph1: kh=0, M-half 1 (B reused) ----
#pragma unroll
    for (int m = 0; m < 4; ++m) a1[m] = A_FRAG(4 + m, h);
    __builtin_amdgcn_s_setprio(1);
#pragma unroll
    for (int m = 0; m < 4; ++m)
#pragma unroll
      for (int n = 0; n < 4; ++n)
        acc[4 + m][n] = __builtin_amdgcn_mfma_f32_16x16x32_bf16(a1[m], bf0[n], acc[4 + m][n], 0, 0, 0);
    __builtin_amdgcn_s_setprio(0);
    // ---- stage next tile's B mid-tile (no reader until kt+1) ----
    if (kt < KTILES - 1) STAGE_B(cur ^ 1, (kt + 1) * 64);
    // ---- ph2: kh=1, M-half 0 ----
#pragma unroll
    for (int m = 0; m < 4; ++m) a0[m] = A_FRAG(m, 4 + h);
#pragma unroll
    for (int n = 0; n < 4; ++n) bf0[n] = B_FRAG(n, 4 + h);
    __builtin_amdgcn_s_setprio(1);
#pragma unroll
    for (int m = 0; m < 4; ++m)
#pragma unroll
      for (int n = 0; n < 4; ++n)
        acc[m][n] = __builtin_amdgcn_mfma_f32_16x16x32_bf16(a0[m], bf0[n], acc[m][n], 0, 0, 0);
    __builtin_amdgcn_s_setprio(0);
    // ---- ph3: kh=1, M-half 1 (B reused) ----
#pragma unroll
    for (int m = 0; m < 4; ++m) a1[m] = A_FRAG(4 + m, 4 + h);
    __builtin_amdgcn_s_setprio(1);
#pragma unroll
    for (int m = 0; m < 4; ++m)
#pragma unroll
      for (int n = 0; n < 4; ++n)
        acc[4 + m][n] = __builtin_amdgcn_mfma_f32_16x16x32_bf16(a1[m], bf0[n], acc[4 + m][n], 0, 0, 0);
    __builtin_amdgcn_s_setprio(0);
    cur ^= 1;
  }
#undef STAGE_A
#undef STAGE_B
#undef A_FRAG
#undef B_FRAG

  // epilogue: lams = softplus(hmu + lam1); loglik partial = obs*log(lams) - lams
  float lsum = 0.f;
  float* lams = out + 1;
#pragma unroll
  for (int mi = 0; mi < 8; ++mi) {
    int krow0 = kb * 256 + wm * 128 + mi * 16 + h * 4;
#pragma unroll
    for (int ni = 0; ni < 4; ++ni) {
      int t = tb * 256 + wn * 64 + ni * 16 + r15;
#pragma unroll
      for (int r = 0; r < 4; ++r) {
        int krow = krow0 + r;
        float x = hmu[krow] + acc[mi][ni][r];
        // stable cheap softplus: max(x,0) + log(1 + exp(-|x|))
        float lam = fmaxf(x, 0.f) + __logf(1.f + __expf(-fabsf(x)));
        lams[(size_t)krow * NDIM + t] = lam;
        float o = (float)obs8[(size_t)krow * NDIM + t];
        lsum += o * __logf(lam) - lam;
      }
    }
  }
  // reduce loglik
  lsum += __shfl_down(lsum, 32);
  lsum += __shfl_down(lsum, 16);
  lsum += __shfl_down(lsum, 8);
  lsum += __shfl_down(lsum, 4);
  lsum += __shfl_down(lsum, 2);
  lsum += __shfl_down(lsum, 1);
  __shared__ float wsum[8];
  if (lane == 0) wsum[wid] = lsum;
  __syncthreads();
  if (tid == 0) {
    float s = 0.f;
#pragma unroll
    for (int w = 0; w < 8; ++w) s += wsum[w];
    atomicAdd(out, s);
  }
}

extern "C" void kernel_launch(void* const* d_in, const int* in_sizes, int n_in,
                              void* d_out, int out_size, void* d_ws, size_t ws_size,
                              hipStream_t stream) {
  const float* obs    = (const float*)d_in[0];
  const float* halpha = (const float*)d_in[1];
  const float* hbeta  = (const float*)d_in[2];
  float* out = (float*)d_out;

  char* ws = (char*)d_ws;
  bf16_t* S_all = (bf16_t*)ws;                                   // 32 MB, [NDIM][KDIM]
  float*  carry = (float*)(ws + (size_t)NDIM * KDIM * 2);        // 1 MB, [K][CHUNKS]
  float*  psum  = carry + (size_t)KDIM * CHUNKS;                 // 1 MB
  float*  hmu   = psum + (size_t)KDIM * CHUNKS;                  // 4 KB
  bf16_t* Ab    = (bf16_t*)(hmu + KDIM);                         // 2 MB
  unsigned char* obs8 = (unsigned char*)(Ab + (size_t)KDIM * KDIM);  // 16.8 MB

  hipMemsetAsync(d_out, 0, sizeof(float), stream);               // loglik accumulator
  k_phase1<<<2048, 256, 0, stream>>>(obs, hbeta, carry, psum, halpha, Ab, obs8);
  k_phase2<<<16, 64, 0, stream>>>(hbeta, carry, psum, hmu);
  k_phase3<<<(KDIM / 64) * CHUNKS, 64, 0, stream>>>(obs8, hbeta, carry, S_all);
  k_gemm<<<4 * (NDIM / 256), 512, 0, stream>>>(Ab, S_all, hmu, obs8, out);
}